// Round 1
// baseline (73.126 us; speedup 1.0000x reference)
//
#include <hip/hip_runtime.h>
#include <hip/hip_bf16.h>

// FeaturesLinear: out[b] = sum_f W[x[b,f] + offsets[f]] + bias
// B=65536, F=26, W: (1040000, 1) fp32, out: (65536, 1) fp32.
// Gather-reduce; W table (4.16 MB) is L2-resident. One thread per row.

#define NUM_FIELDS 26
#define BATCH 65536

__global__ __launch_bounds__(256) void FeaturesLinear_kernel(
    const int* __restrict__ x,        // (B, F) row-major
    const int* __restrict__ offsets,  // (F,)
    const float* __restrict__ W,      // (FEATURE_DIM, 1)
    const float* __restrict__ bias,   // (1,)
    float* __restrict__ out,          // (B, 1)
    int batch) {
  int b = blockIdx.x * blockDim.x + threadIdx.x;
  if (b >= batch) return;

  const int* xr = x + b * NUM_FIELDS;

  // Gather indices first (independent loads, let the compiler batch them),
  // then gather W rows.
  int idx[NUM_FIELDS];
#pragma unroll
  for (int f = 0; f < NUM_FIELDS; ++f) {
    idx[f] = xr[f] + offsets[f];  // offsets: wave-uniform address -> scalar/L1 broadcast
  }

  float s = 0.f;
#pragma unroll
  for (int f = 0; f < NUM_FIELDS; ++f) {
    s += W[idx[f]];
  }

  out[b] = s + bias[0];
}

extern "C" void kernel_launch(void* const* d_in, const int* in_sizes, int n_in,
                              void* d_out, int out_size, void* d_ws, size_t ws_size,
                              hipStream_t stream) {
  const int* x = (const int*)d_in[0];
  const int* offsets = (const int*)d_in[1];
  const float* W = (const float*)d_in[2];
  const float* bias = (const float*)d_in[3];
  float* out = (float*)d_out;

  int batch = in_sizes[0] / NUM_FIELDS;  // 65536

  dim3 block(256);
  dim3 grid((batch + 255) / 256);
  FeaturesLinear_kernel<<<grid, block, 0, stream>>>(x, offsets, W, bias, out, batch);
}